// Round 17
// baseline (504.157 us; speedup 1.0000x reference)
//
#include <hip/hip_runtime.h>
#include <hip/hip_bf16.h>

#define VOCAB 50257
#define CVOCAB 64
#define OUTW (VOCAB + CVOCAB)   // 50321
#define DDIM 1024
#define NROWS 2048
#define SLEN 128
#define NVT 393                  // fallback path: ceil(50257/128)
#define NVT2 197                 // fast path: ceil(50257/256)
#define VOCABP2 (NVT2 * 256)     // 50432 padded vocab rows
#define RSTRIDE 72               // LDS row stride: 64B data + 8B pad (9 pairs, coprime 16)

typedef __attribute__((ext_vector_type(8))) short bf16x8;
typedef __attribute__((ext_vector_type(4))) float f32x4;
typedef __attribute__((ext_vector_type(2))) unsigned long long u64x2;
typedef __attribute__((ext_vector_type(8))) int i32x8;

#if __has_builtin(__builtin_amdgcn_mfma_scale_f32_16x16x128_f8f6f4)
#define MXOK 1
#else
#define MXOK 0
#endif

__device__ __forceinline__ unsigned short f2bf(float f) {
  union { float f; unsigned u; } x; x.f = f;
  unsigned r = x.u + 0x7FFFu + ((x.u >> 16) & 1u);
  return (unsigned short)(r >> 16);
}

// f32 -> OCP e4m3fn, RTE, clamp to 448
__device__ __forceinline__ unsigned char f2e4m3(float f) {
  unsigned u = __float_as_uint(f);
  unsigned s = (u >> 24) & 0x80u;
  float a = __uint_as_float(u & 0x7FFFFFFFu);
  if (!(a < 448.f)) a = 448.f;
  if (a < 0.015625f) {
    int q = (int)rintf(a * 512.f);
    return (unsigned char)(s | (unsigned)q);
  }
  unsigned b = __float_as_uint(a);
  unsigned lsb = (b >> 20) & 1u;
  b += 0x0007FFFFu + lsb;
  int e = (int)((b >> 23) & 0xFF) - 127;
  unsigned m = (b >> 20) & 7u;
  return (unsigned char)(s | ((unsigned)(e + 7) << 3) | m);
}

__device__ __forceinline__ unsigned pack_e4m3x4(float a, float b, float c, float d) {
#if __has_builtin(__builtin_amdgcn_cvt_pk_fp8_f32)
  int r = __builtin_amdgcn_cvt_pk_fp8_f32(a, b, 0, false);
  r = __builtin_amdgcn_cvt_pk_fp8_f32(c, d, r, true);
  return (unsigned)r;
#else
  return (unsigned)f2e4m3(a) | ((unsigned)f2e4m3(b) << 8) |
         ((unsigned)f2e4m3(c) << 16) | ((unsigned)f2e4m3(d) << 24);
#endif
}

__device__ __forceinline__ i32x8 mk8(unsigned long long x0, unsigned long long x1,
                                     unsigned long long x2, unsigned long long x3) {
  i32x8 r;
  r[0] = (int)x0; r[1] = (int)(x0 >> 32);
  r[2] = (int)x1; r[3] = (int)(x1 >> 32);
  r[4] = (int)x2; r[5] = (int)(x2 >> 32);
  r[6] = (int)x3; r[7] = (int)(x3 >> 32);
  return r;
}

// ---------------- p_copy = sigmoid(hidden @ W_copy^T + b_copy) ----------------
__global__ __launch_bounds__(256) void k_pcopy(const float* __restrict__ hidden,
                                               const float* __restrict__ Wc,
                                               const float* __restrict__ bc,
                                               float* __restrict__ pc) {
  int n = blockIdx.x * 4 + (threadIdx.x >> 6);
  int lane = threadIdx.x & 63;
  const float4* h = (const float4*)(hidden + (size_t)n * DDIM);
  const float4* w = (const float4*)Wc;
  float s = 0.0f;
  for (int i = lane; i < DDIM / 4; i += 64) {
    float4 a = h[i], b = w[i];
    s += a.x * b.x + a.y * b.y + a.z * b.z + a.w * b.w;
  }
  #pragma unroll
  for (int m = 1; m < 64; m <<= 1) s += __shfl_xor(s, m);
  if (lane == 0) pc[n] = 1.0f / (1.0f + __expf(-(s + bc[0])));
}

// ---------------- f32 -> fp8 pre-conversion ----------------------------------
__global__ __launch_bounds__(256) void k_cvtA8(const float* __restrict__ src,
                                               unsigned char* __restrict__ dst) {
  int i = blockIdx.x * 256 + threadIdx.x;
  float4 v = *(const float4*)(src + (size_t)i * 4);
  *(unsigned*)(dst + (size_t)i * 4) = pack_e4m3x4(v.x, v.y, v.z, v.w);
}

__global__ __launch_bounds__(256) void k_cvtW8(const float* __restrict__ Wg,
                                               unsigned char* __restrict__ Wf8) {
  int row = blockIdx.x;
  int t = threadIdx.x;
  unsigned r = 0;
  if (row < VOCAB) {
    float4 v = *(const float4*)(Wg + (size_t)row * DDIM + t * 4);
    r = pack_e4m3x4(v.x * 64.f, v.y * 64.f, v.z * 64.f, v.w * 64.f);  // W scaled x64
  }
  *(unsigned*)(Wf8 + (size_t)row * DDIM + t * 4) = r;
}

// ---------------- 256x256 fp8 GEMM: e = exp((A@W64^T)/64 + bg) ---------------
// r16 structure + 2-phase-ahead staging: phase t issues LOAD(t+2) into reg
// set[t&1] and ds-writes set[(t+1)&1] (loaded a full phase earlier, so its
// vmcnt wait is covered by the intervening ds_reads + 32 MX-MFMA). One
// barrier per tile. MX path: 32 mfma_scale 16x16x128 per K-tile pair with
// E8M0=1.0 scales (opsel-robust); fallback = 128 plain 16x16x32 fp8.
template<int OM>
__global__ __launch_bounds__(512, 2) void k_gemm8(const unsigned char* __restrict__ A,
                                                  const unsigned char* __restrict__ W,
                                                  const float* __restrict__ bg,
                                                  float* __restrict__ out,
                                                  unsigned short* __restrict__ ebuf,
                                                  float* __restrict__ partial) {
  __shared__ __align__(16) unsigned char sA[2][256 * RSTRIDE];
  __shared__ __align__(16) unsigned char sB[2][256 * RSTRIDE];
  __shared__ float psum[1024];

  const int tid = threadIdx.x;
  const int lane = tid & 63;
  const int w = tid >> 6;          // 0..7
  const int wr = w >> 2, wn = w & 3;
  const int lrow = lane & 15, kgrp = lane >> 4;

  // bijective XCD swizzle: 1576 = 8 * 197
  int swz = (blockIdx.x & 7) * 197 + (blockIdx.x >> 3);
  const int mt = swz & 7, vt = swz >> 3;
  const int m0 = mt * 256;
  const int v0 = vt * 256;

  // staging: chunk q = tid handles rows q>>2 (and +128), 16B col (q&3)*16
  const int srow = tid >> 2, scol = (tid & 3) * 16;
  const size_t gA0 = (size_t)(m0 + srow) * DDIM + scol;
  const size_t gA1 = gA0 + (size_t)128 * DDIM;
  const size_t gW0 = (size_t)(v0 + srow) * DDIM + scol;
  const size_t gW1 = gW0 + (size_t)128 * DDIM;
  const int l0 = srow * RSTRIDE + scol;
  const int l1 = l0 + 128 * RSTRIDE;

  // frag read byte-offsets (+ s*32 at use site)
  int aoff[8], boff[4];
  #pragma unroll
  for (int rf = 0; rf < 8; rf++)
    aoff[rf] = (wr * 128 + rf * 16 + lrow) * RSTRIDE + kgrp * 8;
  #pragma unroll
  for (int cf = 0; cf < 4; cf++)
    boff[cf] = (wn * 64 + cf * 16 + lrow) * RSTRIDE + kgrp * 8;

  f32x4 acc[8][4] = {};

  // two named staging sets (rule #20: no runtime-indexed reg arrays)
  u64x2 sa0, sa1, sb0, sb1;   // set0: loaded in even phases
  u64x2 ta0, ta1, tb0, tb1;   // set1: loaded in odd phases / prologue
  unsigned long long ae0[8], ae1[8], be0[4], be1[4];   // even-tile stash

  #define LOAD0(t) { \
    sa0 = *(const u64x2*)(A + gA0 + (t) * 64); \
    sa1 = *(const u64x2*)(A + gA1 + (t) * 64); \
    sb0 = *(const u64x2*)(W + gW0 + (t) * 64); \
    sb1 = *(const u64x2*)(W + gW1 + (t) * 64); \
  }
  #define LOAD1(t) { \
    ta0 = *(const u64x2*)(A + gA0 + (t) * 64); \
    ta1 = *(const u64x2*)(A + gA1 + (t) * 64); \
    tb0 = *(const u64x2*)(W + gW0 + (t) * 64); \
    tb1 = *(const u64x2*)(W + gW1 + (t) * 64); \
  }
  #define WRITE0(buf) { \
    unsigned char* da = &sA[buf][0]; \
    unsigned char* db = &sB[buf][0]; \
    *(unsigned long long*)(da + l0)     = sa0[0]; \
    *(unsigned long long*)(da + l0 + 8) = sa0[1]; \
    *(unsigned long long*)(da + l1)     = sa1[0]; \
    *(unsigned long long*)(da + l1 + 8) = sa1[1]; \
    *(unsigned long long*)(db + l0)     = sb0[0]; \
    *(unsigned long long*)(db + l0 + 8) = sb0[1]; \
    *(unsigned long long*)(db + l1)     = sb1[0]; \
    *(unsigned long long*)(db + l1 + 8) = sb1[1]; \
  }
  #define WRITE1(buf) { \
    unsigned char* da = &sA[buf][0]; \
    unsigned char* db = &sB[buf][0]; \
    *(unsigned long long*)(da + l0)     = ta0[0]; \
    *(unsigned long long*)(da + l0 + 8) = ta0[1]; \
    *(unsigned long long*)(da + l1)     = ta1[0]; \
    *(unsigned long long*)(da + l1 + 8) = ta1[1]; \
    *(unsigned long long*)(db + l0)     = tb0[0]; \
    *(unsigned long long*)(db + l0 + 8) = tb0[1]; \
    *(unsigned long long*)(db + l1)     = tb1[0]; \
    *(unsigned long long*)(db + l1 + 8) = tb1[1]; \
  }

  // prologue: tile0 via set0 -> buf0; tile1 preloaded into set1
  LOAD0(0);
  WRITE0(0);
  LOAD1(1);
  asm volatile("s_waitcnt lgkmcnt(0)" ::: "memory");
  __builtin_amdgcn_s_barrier();

  for (int tp = 0; tp < 8; tp++) {
    const int t = tp * 2;
    // ---- even phase (tile t, buf0): LOAD(t+2)->set0; stash frags;
    //      WRITE set1 (tile t+1, loaded last phase) -> buf1 ----
    {
      if (tp < 7) LOAD0(t + 2);
      const unsigned char* pa = &sA[0][0];
      const unsigned char* pb = &sB[0][0];
      #pragma unroll
      for (int rf = 0; rf < 8; rf++) {
        ae0[rf] = *(const unsigned long long*)(pa + aoff[rf]);
        ae1[rf] = *(const unsigned long long*)(pa + aoff[rf] + 32);
      }
      #pragma unroll
      for (int cf = 0; cf < 4; cf++) {
        be0[cf] = *(const unsigned long long*)(pb + boff[cf]);
        be1[cf] = *(const unsigned long long*)(pb + boff[cf] + 32);
      }
      WRITE1(1);
      asm volatile("s_waitcnt lgkmcnt(0)" ::: "memory");
      __builtin_amdgcn_s_barrier();
    }
    // ---- odd phase (tile t+1, buf1): LOAD(t+3)->set1; read frags;
    //      32 MX-MFMA; WRITE set0 (tile t+2) -> buf0 ----
    {
      if (tp < 7) LOAD1(t + 3);
      const unsigned char* pa = &sA[1][0];
      const unsigned char* pb = &sB[1][0];
      unsigned long long ao0[8], ao1[8], bo0[4], bo1[4];
      #pragma unroll
      for (int rf = 0; rf < 8; rf++) {
        ao0[rf] = *(const unsigned long long*)(pa + aoff[rf]);
        ao1[rf] = *(const unsigned long long*)(pa + aoff[rf] + 32);
      }
      #pragma unroll
      for (int cf = 0; cf < 4; cf++) {
        bo0[cf] = *(const unsigned long long*)(pb + boff[cf]);
        bo1[cf] = *(const unsigned long long*)(pb + boff[cf] + 32);
      }
      __builtin_amdgcn_s_setprio(1);
#if MXOK
      i32x8 bfr[4];
      #pragma unroll
      for (int cf = 0; cf < 4; cf++)
        bfr[cf] = mk8(be0[cf], be1[cf], bo0[cf], bo1[cf]);
      #pragma unroll
      for (int rf = 0; rf < 8; rf++) {
        i32x8 afr = mk8(ae0[rf], ae1[rf], ao0[rf], ao1[rf]);
        #pragma unroll
        for (int cf = 0; cf < 4; cf++)
          acc[rf][cf] = __builtin_amdgcn_mfma_scale_f32_16x16x128_f8f6f4(
              afr, bfr[cf], acc[rf][cf], 0, 0,
              0, 0x7F7F7F7F, 0, 0x7F7F7F7F);
      }
#else
      #pragma unroll
      for (int rf = 0; rf < 8; rf++)
        #pragma unroll
        for (int cf = 0; cf < 4; cf++) {
          acc[rf][cf] = __builtin_amdgcn_mfma_f32_16x16x32_fp8_fp8(
              (long)ae0[rf], (long)be0[cf], acc[rf][cf], 0, 0, 0);
          acc[rf][cf] = __builtin_amdgcn_mfma_f32_16x16x32_fp8_fp8(
              (long)ae1[rf], (long)be1[cf], acc[rf][cf], 0, 0, 0);
          acc[rf][cf] = __builtin_amdgcn_mfma_f32_16x16x32_fp8_fp8(
              (long)ao0[rf], (long)bo0[cf], acc[rf][cf], 0, 0, 0);
          acc[rf][cf] = __builtin_amdgcn_mfma_f32_16x16x32_fp8_fp8(
              (long)ao1[rf], (long)bo1[cf], acc[rf][cf], 0, 0, 0);
        }
#endif
      __builtin_amdgcn_s_setprio(0);
      if (tp < 7) {
        WRITE0(0);
        asm volatile("s_waitcnt lgkmcnt(0)" ::: "memory");
        __builtin_amdgcn_s_barrier();
      }
    }
  }
  #undef LOAD0
  #undef LOAD1
  #undef WRITE0
  #undef WRITE1

  // epilogue
  const float INV = 0.015625f;          // 1/64 (W was scaled x64)
  float bgv[4];
  int vcol[4];
  #pragma unroll
  for (int cf = 0; cf < 4; cf++) {
    vcol[cf] = v0 + wn * 64 + cf * 16 + lrow;
    bgv[cf] = (vcol[cf] < VOCAB) ? bg[vcol[cf]] : 0.0f;
  }
  #pragma unroll
  for (int a = 0; a < 8; a++) {
    #pragma unroll
    for (int r = 0; r < 4; r++) {
      int lr = wr * 128 + a * 16 + kgrp * 4 + r;
      int row = m0 + lr;
      float s = 0.0f;
      #pragma unroll
      for (int cf = 0; cf < 4; cf++) {
        int v = vcol[cf];
        float e = 0.0f;
        if (v < VOCAB && v != 0) e = __expf(acc[a][cf][r] * INV + bgv[cf]);
        if (OM == 0) {
          if (v < VOCAB) out[(size_t)row * OUTW + v] = e;
        } else {
          if (v < VOCAB) ebuf[(size_t)row * VOCABP2 + v + (row & 3)] = f2bf(e);
        }
        s += e;
      }
      s += __shfl_xor(s, 1); s += __shfl_xor(s, 2);
      s += __shfl_xor(s, 4); s += __shfl_xor(s, 8);
      if (lrow == 0) psum[wn * 256 + lr] = s;
    }
  }
  __syncthreads();
  if (tid < 256)
    partial[(size_t)vt * NROWS + m0 + tid] =
        psum[tid] + psum[256 + tid] + psum[512 + tid] + psum[768 + tid];
}

// ---------------- fallback GEMM (round-1, f32 inputs) ------------------------
__global__ __launch_bounds__(256) void k_gemm(const float* __restrict__ hidden,
                                              const float* __restrict__ Wg,
                                              const float* __restrict__ bg,
                                              float* __restrict__ out,
                                              float* __restrict__ partial) {
  __shared__ __align__(16) unsigned char smemA[128 * 64 * 2];
  __shared__ __align__(16) unsigned char smemB[128 * 64 * 2];
  __shared__ float psum[2][128];

  const int tid = threadIdx.x;
  const int lane = tid & 63;
  const int wid = tid >> 6;
  const int wr = wid >> 1, wc = wid & 1;
  const int lrow = lane & 15, kgrp = lane >> 4;
  const int m0 = blockIdx.x * 128;
  const int vt = blockIdx.y;
  const int v0 = vt * 128;

  f32x4 acc[4][4] = {};

  for (int kt = 0; kt < 16; kt++) {
    const int k0 = kt * 64;
    #pragma unroll
    for (int i = 0; i < 8; i++) {
      int f = i * 256 + tid;
      int row = f >> 4;
      int kq = (f & 15) << 2;
      float4 v = *(const float4*)(hidden + (size_t)(m0 + row) * DDIM + k0 + kq);
      ushort4 h;
      h.x = f2bf(v.x); h.y = f2bf(v.y); h.z = f2bf(v.z); h.w = f2bf(v.w);
      *(ushort4*)(smemA + row * 128 + ((kq << 1) ^ ((row & 7) << 4))) = h;
    }
    #pragma unroll
    for (int i = 0; i < 8; i++) {
      int f = i * 256 + tid;
      int row = f >> 4;
      int kq = (f & 15) << 2;
      float4 v = make_float4(0.f, 0.f, 0.f, 0.f);
      if (v0 + row < VOCAB)
        v = *(const float4*)(Wg + (size_t)(v0 + row) * DDIM + k0 + kq);
      ushort4 h;
      h.x = f2bf(v.x); h.y = f2bf(v.y); h.z = f2bf(v.z); h.w = f2bf(v.w);
      *(ushort4*)(smemB + row * 128 + ((kq << 1) ^ ((row & 7) << 4))) = h;
    }
    __syncthreads();
    #pragma unroll
    for (int ks = 0; ks < 2; ks++) {
      const int kb = (ks * 32 + kgrp * 8) * 2;
      bf16x8 af[4], bfr[4];
      #pragma unroll
      for (int i = 0; i < 4; i++) {
        int ar = wr * 64 + i * 16 + lrow;
        af[i] = *(const bf16x8*)(smemA + ar * 128 + (kb ^ ((ar & 7) << 4)));
        int br = wc * 64 + i * 16 + lrow;
        bfr[i] = *(const bf16x8*)(smemB + br * 128 + (kb ^ ((br & 7) << 4)));
      }
      #pragma unroll
      for (int i = 0; i < 4; i++)
        #pragma unroll
        for (int j = 0; j < 4; j++)
          acc[i][j] = __builtin_amdgcn_mfma_f32_16x16x32_bf16(af[i], bfr[j], acc[i][j], 0, 0, 0);
    }
    __syncthreads();
  }

  float bgv[4];
  int vcol[4];
  #pragma unroll
  for (int j = 0; j < 4; j++) {
    vcol[j] = v0 + wc * 64 + j * 16 + lrow;
    bgv[j] = (vcol[j] < VOCAB) ? bg[vcol[j]] : 0.0f;
  }
  #pragma unroll
  for (int i = 0; i < 4; i++) {
    #pragma unroll
    for (int r = 0; r < 4; r++) {
      int row = m0 + wr * 64 + i * 16 + kgrp * 4 + r;
      float s = 0.0f;
      #pragma unroll
      for (int j = 0; j < 4; j++) {
        int v = vcol[j];
        float e = 0.0f;
        if (v < VOCAB && v != 0) e = __expf(acc[i][j][r] + bgv[j]);
        if (v < VOCAB) out[(size_t)row * OUTW + v] = e;
        s += e;
      }
      s += __shfl_xor(s, 1); s += __shfl_xor(s, 2);
      s += __shfl_xor(s, 4); s += __shfl_xor(s, 8);
      if ((lane & 15) == 0) psum[wc][wr * 64 + i * 16 + kgrp * 4 + r] = s;
    }
  }
  __syncthreads();
  if (tid < 128)
    partial[(size_t)vt * NROWS + m0 + tid] = psum[0][tid] + psum[1][tid];
}

// ---------------- reduce partials -> scale = (1-pc)/sum ----------------------
// 256 blocks x 8 rows; 32-lane slice per row (latency-parallel).
__global__ __launch_bounds__(256) void k_reduce(const float* __restrict__ partial,
                                                const float* __restrict__ pc,
                                                float* __restrict__ scale, int nvt) {
  int row = blockIdx.x * 8 + (threadIdx.x >> 5);
  int sl = threadIdx.x & 31;
  float s = 0.0f;
  for (int t = sl; t < nvt; t += 32) s += partial[(size_t)t * NROWS + row];
  s += __shfl_xor(s, 1); s += __shfl_xor(s, 2); s += __shfl_xor(s, 4);
  s += __shfl_xor(s, 8); s += __shfl_xor(s, 16);
  if (sl == 0) scale[row] = (1.0f - pc[row]) / s;
}

// ---------------- tier-1: scale gen region in place --------------------------
__global__ __launch_bounds__(256) void k_scale(float* __restrict__ out,
                                               const float* __restrict__ scale) {
  int n = blockIdx.x;
  float sc = scale[n];
  size_t base = (size_t)n * OUTW;
  int off = (int)((4 - (base & 3)) & 3);
  for (int c = threadIdx.x; c < off; c += 256) out[base + c] *= sc;
  int nv = (VOCAB - off) >> 2;
  f32x4* p = (f32x4*)(out + base + off);
  for (int i = threadIdx.x; i < nv; i += 256) {
    f32x4 v = p[i];
    v *= sc;
    __builtin_nontemporal_store(v, &p[i]);
  }
  for (int c = off + (nv << 2) + threadIdx.x; c < VOCAB; c += 256) out[base + c] *= sc;
}

// ---------------- tier-2: expand shifted bf16 ebuf -> scaled f32 out ---------
__global__ __launch_bounds__(256) void k_scale2(const unsigned short* __restrict__ ebuf,
                                                const float* __restrict__ scale,
                                                float* __restrict__ out) {
  int n = blockIdx.x;
  float sc = scale[n];
  const int shift = n & 3;
  const int off = (4 - shift) & 3;
  const unsigned short* er = ebuf + (size_t)n * VOCABP2 + shift;
  float* orow = out + (size_t)n * OUTW;
  for (int c = threadIdx.x; c < off; c += 256)
    orow[c] = __uint_as_float((unsigned)er[c] << 16) * sc;
  int nv = (VOCAB - off) >> 2;
  for (int i = threadIdx.x; i < nv; i += 256) {
    int c = off + i * 4;
    ushort4 v = *(const ushort4*)(er + c);      // byte offset % 8 == 0
    f32x4 f;
    f.x = __uint_as_float((unsigned)v.x << 16) * sc;
    f.y = __uint_as_float((unsigned)v.y << 16) * sc;
    f.z = __uint_as_float((unsigned)v.z << 16) * sc;
    f.w = __uint_as_float((unsigned)v.w << 16) * sc;
    __builtin_nontemporal_store(f, (f32x4*)(orow + c));
  }
  for (int c = off + (nv << 2) + threadIdx.x; c < VOCAB; c += 256)
    orow[c] = __uint_as_float((unsigned)er[c] << 16) * sc;
}

// ---------------- copy probs: out[:, VOCAB:] = (attn*pc) @ src_map -----------
__global__ __launch_bounds__(64) void k_copy(const float* __restrict__ attn,
                                             const float* __restrict__ src_map,
                                             const float* __restrict__ pc,
                                             float* __restrict__ out) {
  int n = blockIdx.x;
  int c = threadIdx.x;  // 0..63
  int b = n & 31;
  __shared__ float arow[SLEN];
  arow[c] = attn[(size_t)n * SLEN + c];
  arow[c + 64] = attn[(size_t)n * SLEN + 64 + c];
  __syncthreads();
  float s = 0.0f;
  for (int sp = 0; sp < SLEN; sp++)
    s += arow[sp] * src_map[((size_t)sp * 32 + b) * CVOCAB + c];
  out[(size_t)n * OUTW + VOCAB + c] = s * pc[n];
}

extern "C" void kernel_launch(void* const* d_in, const int* in_sizes, int n_in,
                              void* d_out, int out_size, void* d_ws, size_t ws_size,
                              hipStream_t stream) {
  const float* hidden = (const float*)d_in[0];
  const float* attn   = (const float*)d_in[1];
  const float* srcmap = (const float*)d_in[2];
  const float* Wg     = (const float*)d_in[3];
  const float* bg     = (const float*)d_in[4];
  const float* Wc     = (const float*)d_in[5];
  const float* bc     = (const float*)d_in[6];
  float* out = (float*)d_out;

  char* ws = (char*)d_ws;
  float* pc      = (float*)ws;                       // 2048 f32
  float* scale   = (float*)(ws + 8192);              // 2048 f32
  float* partial = (float*)(ws + 16384);             // NVT*2048 f32 (max)
  size_t partEnd = 16384 + (size_t)NVT * NROWS * 4;  // 3,235,840
  unsigned char* A8 = (unsigned char*)(ws + partEnd);            // 2 MB
  size_t aEnd = partEnd + (size_t)NROWS * DDIM;
  unsigned char* W8 = (unsigned char*)(ws + aEnd);               // 51.6 MB
  size_t wEnd = aEnd + (size_t)VOCABP2 * DDIM;
  unsigned short* ebuf = (unsigned short*)(ws + wEnd);           // 206.6 MB
  size_t need1 = wEnd;
  size_t need2 = wEnd + (size_t)NROWS * VOCABP2 * 2;

  k_pcopy<<<NROWS / 4, 256, 0, stream>>>(hidden, Wc, bc, pc);
  if (ws_size >= need1) {
    k_cvtA8<<<(NROWS * DDIM / 4) / 256, 256, 0, stream>>>(hidden, A8);
    k_cvtW8<<<VOCABP2, 256, 0, stream>>>(Wg, W8);
    if (ws_size >= need2) {
      k_gemm8<1><<<8 * NVT2, 512, 0, stream>>>(A8, W8, bg, out, ebuf, partial);
      k_reduce<<<NROWS / 8, 256, 0, stream>>>(partial, pc, scale, NVT2);
      k_scale2<<<NROWS, 256, 0, stream>>>(ebuf, scale, out);
    } else {
      k_gemm8<0><<<8 * NVT2, 512, 0, stream>>>(A8, W8, bg, out, ebuf, partial);
      k_reduce<<<NROWS / 8, 256, 0, stream>>>(partial, pc, scale, NVT2);
      k_scale<<<NROWS, 256, 0, stream>>>(out, scale);
    }
  } else {
    k_gemm<<<dim3(NROWS / 128, NVT), 256, 0, stream>>>(hidden, Wg, bg, out, partial);
    k_reduce<<<NROWS / 8, 256, 0, stream>>>(partial, pc, scale, NVT);
    k_scale<<<NROWS, 256, 0, stream>>>(out, scale);
  }
  k_copy<<<NROWS, 64, 0, stream>>>(attn, srcmap, pc, out);
}

// Round 18
// 409.417 us; speedup vs baseline: 1.2314x; 1.2314x over previous
//
#include <hip/hip_runtime.h>
#include <hip/hip_bf16.h>

#define VOCAB 50257
#define CVOCAB 64
#define OUTW (VOCAB + CVOCAB)   // 50321
#define DDIM 1024
#define NROWS 2048
#define SLEN 128
#define NVT 393                  // fallback path: ceil(50257/128)
#define NVT2 197                 // fast path: ceil(50257/256)
#define VOCABP2 (NVT2 * 256)     // 50432 padded vocab rows
#define RSTRIDE 72               // LDS row stride: 64B data + 8B pad (9 pairs, coprime 16)

typedef __attribute__((ext_vector_type(8))) short bf16x8;
typedef __attribute__((ext_vector_type(4))) float f32x4;
typedef __attribute__((ext_vector_type(2))) unsigned long long u64x2;
typedef __attribute__((ext_vector_type(8))) int i32x8;

#if __has_builtin(__builtin_amdgcn_mfma_scale_f32_16x16x128_f8f6f4)
#define MXOK 1
#else
#define MXOK 0
#endif

__device__ __forceinline__ unsigned short f2bf(float f) {
  union { float f; unsigned u; } x; x.f = f;
  unsigned r = x.u + 0x7FFFu + ((x.u >> 16) & 1u);
  return (unsigned short)(r >> 16);
}

// f32 -> OCP e4m3fn, RTE, clamp to 448
__device__ __forceinline__ unsigned char f2e4m3(float f) {
  unsigned u = __float_as_uint(f);
  unsigned s = (u >> 24) & 0x80u;
  float a = __uint_as_float(u & 0x7FFFFFFFu);
  if (!(a < 448.f)) a = 448.f;
  if (a < 0.015625f) {
    int q = (int)rintf(a * 512.f);
    return (unsigned char)(s | (unsigned)q);
  }
  unsigned b = __float_as_uint(a);
  unsigned lsb = (b >> 20) & 1u;
  b += 0x0007FFFFu + lsb;
  int e = (int)((b >> 23) & 0xFF) - 127;
  unsigned m = (b >> 20) & 7u;
  return (unsigned char)(s | ((unsigned)(e + 7) << 3) | m);
}

__device__ __forceinline__ unsigned pack_e4m3x4(float a, float b, float c, float d) {
#if __has_builtin(__builtin_amdgcn_cvt_pk_fp8_f32)
  int r = __builtin_amdgcn_cvt_pk_fp8_f32(a, b, 0, false);
  r = __builtin_amdgcn_cvt_pk_fp8_f32(c, d, r, true);
  return (unsigned)r;
#else
  return (unsigned)f2e4m3(a) | ((unsigned)f2e4m3(b) << 8) |
         ((unsigned)f2e4m3(c) << 16) | ((unsigned)f2e4m3(d) << 24);
#endif
}

__device__ __forceinline__ i32x8 mk8(unsigned long long x0, unsigned long long x1,
                                     unsigned long long x2, unsigned long long x3) {
  i32x8 r;
  r[0] = (int)x0; r[1] = (int)(x0 >> 32);
  r[2] = (int)x1; r[3] = (int)(x1 >> 32);
  r[4] = (int)x2; r[5] = (int)(x2 >> 32);
  r[6] = (int)x3; r[7] = (int)(x3 >> 32);
  return r;
}

// ---------------- p_copy = sigmoid(hidden @ W_copy^T + b_copy) ----------------
__global__ __launch_bounds__(256) void k_pcopy(const float* __restrict__ hidden,
                                               const float* __restrict__ Wc,
                                               const float* __restrict__ bc,
                                               float* __restrict__ pc) {
  int n = blockIdx.x * 4 + (threadIdx.x >> 6);
  int lane = threadIdx.x & 63;
  const float4* h = (const float4*)(hidden + (size_t)n * DDIM);
  const float4* w = (const float4*)Wc;
  float s = 0.0f;
  for (int i = lane; i < DDIM / 4; i += 64) {
    float4 a = h[i], b = w[i];
    s += a.x * b.x + a.y * b.y + a.z * b.z + a.w * b.w;
  }
  #pragma unroll
  for (int m = 1; m < 64; m <<= 1) s += __shfl_xor(s, m);
  if (lane == 0) pc[n] = 1.0f / (1.0f + __expf(-(s + bc[0])));
}

// ---------------- f32 -> fp8 pre-conversion ----------------------------------
__global__ __launch_bounds__(256) void k_cvtA8(const float* __restrict__ src,
                                               unsigned char* __restrict__ dst) {
  int i = blockIdx.x * 256 + threadIdx.x;
  float4 v = *(const float4*)(src + (size_t)i * 4);
  *(unsigned*)(dst + (size_t)i * 4) = pack_e4m3x4(v.x, v.y, v.z, v.w);
}

__global__ __launch_bounds__(256) void k_cvtW8(const float* __restrict__ Wg,
                                               unsigned char* __restrict__ Wf8) {
  int row = blockIdx.x;
  int t = threadIdx.x;
  unsigned r = 0;
  if (row < VOCAB) {
    float4 v = *(const float4*)(Wg + (size_t)row * DDIM + t * 4);
    r = pack_e4m3x4(v.x * 64.f, v.y * 64.f, v.z * 64.f, v.w * 64.f);  // W scaled x64
  }
  *(unsigned*)(Wf8 + (size_t)row * DDIM + t * 4) = r;
}

// ---------------- 256x256 fp8 GEMM: e = exp((A@W64^T)/64 + bg) ---------------
// r16 schedule (single staging reg set, one barrier per tile) with LOADT
// issued BEFORE the stash/frag ds_reads in each phase: the ~24 ds_read_b64
// per wave (~2300 cyc/CU of LDS pipe) cover the global-load latency, so the
// vmcnt drain before WRITET is no longer exposed. Zero extra registers
// (r17's 2-set variant spilled: VGPR cap 128, +140 MB scratch traffic).
// MX path: 32 mfma_scale 16x16x128 per K-tile pair, E8M0=1.0 scales.
template<int OM>
__global__ __launch_bounds__(512, 2) void k_gemm8(const unsigned char* __restrict__ A,
                                                  const unsigned char* __restrict__ W,
                                                  const float* __restrict__ bg,
                                                  float* __restrict__ out,
                                                  unsigned short* __restrict__ ebuf,
                                                  float* __restrict__ partial) {
  __shared__ __align__(16) unsigned char sA[2][256 * RSTRIDE];
  __shared__ __align__(16) unsigned char sB[2][256 * RSTRIDE];
  __shared__ float psum[1024];

  const int tid = threadIdx.x;
  const int lane = tid & 63;
  const int w = tid >> 6;          // 0..7
  const int wr = w >> 2, wn = w & 3;
  const int lrow = lane & 15, kgrp = lane >> 4;

  // bijective XCD swizzle: 1576 = 8 * 197
  int swz = (blockIdx.x & 7) * 197 + (blockIdx.x >> 3);
  const int mt = swz & 7, vt = swz >> 3;
  const int m0 = mt * 256;
  const int v0 = vt * 256;

  // staging: chunk q = tid handles rows q>>2 (and +128), 16B col (q&3)*16
  const int srow = tid >> 2, scol = (tid & 3) * 16;
  const size_t gA0 = (size_t)(m0 + srow) * DDIM + scol;
  const size_t gA1 = gA0 + (size_t)128 * DDIM;
  const size_t gW0 = (size_t)(v0 + srow) * DDIM + scol;
  const size_t gW1 = gW0 + (size_t)128 * DDIM;
  const int l0 = srow * RSTRIDE + scol;
  const int l1 = l0 + 128 * RSTRIDE;

  // frag read byte-offsets (+ s*32 at use site)
  int aoff[8], boff[4];
  #pragma unroll
  for (int rf = 0; rf < 8; rf++)
    aoff[rf] = (wr * 128 + rf * 16 + lrow) * RSTRIDE + kgrp * 8;
  #pragma unroll
  for (int cf = 0; cf < 4; cf++)
    boff[cf] = (wn * 64 + cf * 16 + lrow) * RSTRIDE + kgrp * 8;

  f32x4 acc[8][4] = {};

  u64x2 ra0, ra1, rb0, rb1;
  unsigned long long ae0[8], ae1[8], be0[4], be1[4];   // even-tile stash

  #define LOADT(t) { \
    ra0 = *(const u64x2*)(A + gA0 + (t) * 64); \
    ra1 = *(const u64x2*)(A + gA1 + (t) * 64); \
    rb0 = *(const u64x2*)(W + gW0 + (t) * 64); \
    rb1 = *(const u64x2*)(W + gW1 + (t) * 64); \
  }
  #define WRITET(buf) { \
    unsigned char* da = &sA[buf][0]; \
    unsigned char* db = &sB[buf][0]; \
    *(unsigned long long*)(da + l0)     = ra0[0]; \
    *(unsigned long long*)(da + l0 + 8) = ra0[1]; \
    *(unsigned long long*)(da + l1)     = ra1[0]; \
    *(unsigned long long*)(da + l1 + 8) = ra1[1]; \
    *(unsigned long long*)(db + l0)     = rb0[0]; \
    *(unsigned long long*)(db + l0 + 8) = rb0[1]; \
    *(unsigned long long*)(db + l1)     = rb1[0]; \
    *(unsigned long long*)(db + l1 + 8) = rb1[1]; \
  }

  // prologue: stage tile 0 into buf 0
  LOADT(0);
  WRITET(0);
  asm volatile("s_waitcnt lgkmcnt(0)" ::: "memory");
  __builtin_amdgcn_s_barrier();

  for (int tp = 0; tp < 8; tp++) {
    const int t = tp * 2;
    // ---- even phase: LOAD(t+1) FIRST; stash frag ds_reads cover its
    //      latency; then WRITET(1); barrier ----
    {
      LOADT(t + 1);
      const unsigned char* pa = &sA[0][0];   // t even -> buf 0
      const unsigned char* pb = &sB[0][0];
      #pragma unroll
      for (int rf = 0; rf < 8; rf++) {
        ae0[rf] = *(const unsigned long long*)(pa + aoff[rf]);
        ae1[rf] = *(const unsigned long long*)(pa + aoff[rf] + 32);
      }
      #pragma unroll
      for (int cf = 0; cf < 4; cf++) {
        be0[cf] = *(const unsigned long long*)(pb + boff[cf]);
        be1[cf] = *(const unsigned long long*)(pb + boff[cf] + 32);
      }
      WRITET(1);
      asm volatile("s_waitcnt lgkmcnt(0)" ::: "memory");
      __builtin_amdgcn_s_barrier();
    }
    // ---- odd phase: LOAD(t+2) FIRST; frag ds_reads; 32 MX-MFMA cover
    //      the write drain; WRITET(0); barrier ----
    {
      const bool pf = (tp < 7);
      if (pf) LOADT(t + 2);
      const unsigned char* pa = &sA[1][0];   // t+1 odd -> buf 1
      const unsigned char* pb = &sB[1][0];
      unsigned long long ao0[8], ao1[8], bo0[4], bo1[4];
      #pragma unroll
      for (int rf = 0; rf < 8; rf++) {
        ao0[rf] = *(const unsigned long long*)(pa + aoff[rf]);
        ao1[rf] = *(const unsigned long long*)(pa + aoff[rf] + 32);
      }
      #pragma unroll
      for (int cf = 0; cf < 4; cf++) {
        bo0[cf] = *(const unsigned long long*)(pb + boff[cf]);
        bo1[cf] = *(const unsigned long long*)(pb + boff[cf] + 32);
      }
      __builtin_amdgcn_s_setprio(1);
#if MXOK
      i32x8 bfr[4];
      #pragma unroll
      for (int cf = 0; cf < 4; cf++)
        bfr[cf] = mk8(be0[cf], be1[cf], bo0[cf], bo1[cf]);
      #pragma unroll
      for (int rf = 0; rf < 8; rf++) {
        i32x8 afr = mk8(ae0[rf], ae1[rf], ao0[rf], ao1[rf]);
        #pragma unroll
        for (int cf = 0; cf < 4; cf++)
          acc[rf][cf] = __builtin_amdgcn_mfma_scale_f32_16x16x128_f8f6f4(
              afr, bfr[cf], acc[rf][cf], 0, 0,
              0, 0x7F7F7F7F, 0, 0x7F7F7F7F);
      }
#else
      #pragma unroll
      for (int rf = 0; rf < 8; rf++)
        #pragma unroll
        for (int cf = 0; cf < 4; cf++) {
          acc[rf][cf] = __builtin_amdgcn_mfma_f32_16x16x32_fp8_fp8(
              (long)ae0[rf], (long)be0[cf], acc[rf][cf], 0, 0, 0);
          acc[rf][cf] = __builtin_amdgcn_mfma_f32_16x16x32_fp8_fp8(
              (long)ae1[rf], (long)be1[cf], acc[rf][cf], 0, 0, 0);
          acc[rf][cf] = __builtin_amdgcn_mfma_f32_16x16x32_fp8_fp8(
              (long)ao0[rf], (long)bo0[cf], acc[rf][cf], 0, 0, 0);
          acc[rf][cf] = __builtin_amdgcn_mfma_f32_16x16x32_fp8_fp8(
              (long)ao1[rf], (long)bo1[cf], acc[rf][cf], 0, 0, 0);
        }
#endif
      __builtin_amdgcn_s_setprio(0);
      if (pf) {
        WRITET(0);
        asm volatile("s_waitcnt lgkmcnt(0)" ::: "memory");
        __builtin_amdgcn_s_barrier();
      }
    }
  }
  #undef LOADT
  #undef WRITET

  // epilogue
  const float INV = 0.015625f;          // 1/64 (W was scaled x64)
  float bgv[4];
  int vcol[4];
  #pragma unroll
  for (int cf = 0; cf < 4; cf++) {
    vcol[cf] = v0 + wn * 64 + cf * 16 + lrow;
    bgv[cf] = (vcol[cf] < VOCAB) ? bg[vcol[cf]] : 0.0f;
  }
  #pragma unroll
  for (int a = 0; a < 8; a++) {
    #pragma unroll
    for (int r = 0; r < 4; r++) {
      int lr = wr * 128 + a * 16 + kgrp * 4 + r;
      int row = m0 + lr;
      float s = 0.0f;
      #pragma unroll
      for (int cf = 0; cf < 4; cf++) {
        int v = vcol[cf];
        float e = 0.0f;
        if (v < VOCAB && v != 0) e = __expf(acc[a][cf][r] * INV + bgv[cf]);
        if (OM == 0) {
          if (v < VOCAB) out[(size_t)row * OUTW + v] = e;
        } else {
          if (v < VOCAB) ebuf[(size_t)row * VOCABP2 + v + (row & 3)] = f2bf(e);
        }
        s += e;
      }
      s += __shfl_xor(s, 1); s += __shfl_xor(s, 2);
      s += __shfl_xor(s, 4); s += __shfl_xor(s, 8);
      if (lrow == 0) psum[wn * 256 + lr] = s;
    }
  }
  __syncthreads();
  if (tid < 256)
    partial[(size_t)vt * NROWS + m0 + tid] =
        psum[tid] + psum[256 + tid] + psum[512 + tid] + psum[768 + tid];
}

// ---------------- fallback GEMM (round-1, f32 inputs) ------------------------
__global__ __launch_bounds__(256) void k_gemm(const float* __restrict__ hidden,
                                              const float* __restrict__ Wg,
                                              const float* __restrict__ bg,
                                              float* __restrict__ out,
                                              float* __restrict__ partial) {
  __shared__ __align__(16) unsigned char smemA[128 * 64 * 2];
  __shared__ __align__(16) unsigned char smemB[128 * 64 * 2];
  __shared__ float psum[2][128];

  const int tid = threadIdx.x;
  const int lane = tid & 63;
  const int wid = tid >> 6;
  const int wr = wid >> 1, wc = wid & 1;
  const int lrow = lane & 15, kgrp = lane >> 4;
  const int m0 = blockIdx.x * 128;
  const int vt = blockIdx.y;
  const int v0 = vt * 128;

  f32x4 acc[4][4] = {};

  for (int kt = 0; kt < 16; kt++) {
    const int k0 = kt * 64;
    #pragma unroll
    for (int i = 0; i < 8; i++) {
      int f = i * 256 + tid;
      int row = f >> 4;
      int kq = (f & 15) << 2;
      float4 v = *(const float4*)(hidden + (size_t)(m0 + row) * DDIM + k0 + kq);
      ushort4 h;
      h.x = f2bf(v.x); h.y = f2bf(v.y); h.z = f2bf(v.z); h.w = f2bf(v.w);
      *(ushort4*)(smemA + row * 128 + ((kq << 1) ^ ((row & 7) << 4))) = h;
    }
    #pragma unroll
    for (int i = 0; i < 8; i++) {
      int f = i * 256 + tid;
      int row = f >> 4;
      int kq = (f & 15) << 2;
      float4 v = make_float4(0.f, 0.f, 0.f, 0.f);
      if (v0 + row < VOCAB)
        v = *(const float4*)(Wg + (size_t)(v0 + row) * DDIM + k0 + kq);
      ushort4 h;
      h.x = f2bf(v.x); h.y = f2bf(v.y); h.z = f2bf(v.z); h.w = f2bf(v.w);
      *(ushort4*)(smemB + row * 128 + ((kq << 1) ^ ((row & 7) << 4))) = h;
    }
    __syncthreads();
    #pragma unroll
    for (int ks = 0; ks < 2; ks++) {
      const int kb = (ks * 32 + kgrp * 8) * 2;
      bf16x8 af[4], bfr[4];
      #pragma unroll
      for (int i = 0; i < 4; i++) {
        int ar = wr * 64 + i * 16 + lrow;
        af[i] = *(const bf16x8*)(smemA + ar * 128 + (kb ^ ((ar & 7) << 4)));
        int br = wc * 64 + i * 16 + lrow;
        bfr[i] = *(const bf16x8*)(smemB + br * 128 + (kb ^ ((br & 7) << 4)));
      }
      #pragma unroll
      for (int i = 0; i < 4; i++)
        #pragma unroll
        for (int j = 0; j < 4; j++)
          acc[i][j] = __builtin_amdgcn_mfma_f32_16x16x32_bf16(af[i], bfr[j], acc[i][j], 0, 0, 0);
    }
    __syncthreads();
  }

  float bgv[4];
  int vcol[4];
  #pragma unroll
  for (int j = 0; j < 4; j++) {
    vcol[j] = v0 + wc * 64 + j * 16 + lrow;
    bgv[j] = (vcol[j] < VOCAB) ? bg[vcol[j]] : 0.0f;
  }
  #pragma unroll
  for (int i = 0; i < 4; i++) {
    #pragma unroll
    for (int r = 0; r < 4; r++) {
      int row = m0 + wr * 64 + i * 16 + kgrp * 4 + r;
      float s = 0.0f;
      #pragma unroll
      for (int j = 0; j < 4; j++) {
        int v = vcol[j];
        float e = 0.0f;
        if (v < VOCAB && v != 0) e = __expf(acc[i][j][r] + bgv[j]);
        if (v < VOCAB) out[(size_t)row * OUTW + v] = e;
        s += e;
      }
      s += __shfl_xor(s, 1); s += __shfl_xor(s, 2);
      s += __shfl_xor(s, 4); s += __shfl_xor(s, 8);
      if ((lane & 15) == 0) psum[wc][wr * 64 + i * 16 + kgrp * 4 + r] = s;
    }
  }
  __syncthreads();
  if (tid < 128)
    partial[(size_t)vt * NROWS + m0 + tid] = psum[0][tid] + psum[1][tid];
}

// ---------------- reduce partials -> scale = (1-pc)/sum ----------------------
// 256 blocks x 8 rows; 32-lane slice per row (latency-parallel).
__global__ __launch_bounds__(256) void k_reduce(const float* __restrict__ partial,
                                                const float* __restrict__ pc,
                                                float* __restrict__ scale, int nvt) {
  int row = blockIdx.x * 8 + (threadIdx.x >> 5);
  int sl = threadIdx.x & 31;
  float s = 0.0f;
  for (int t = sl; t < nvt; t += 32) s += partial[(size_t)t * NROWS + row];
  s += __shfl_xor(s, 1); s += __shfl_xor(s, 2); s += __shfl_xor(s, 4);
  s += __shfl_xor(s, 8); s += __shfl_xor(s, 16);
  if (sl == 0) scale[row] = (1.0f - pc[row]) / s;
}

// ---------------- tier-1: scale gen region in place --------------------------
__global__ __launch_bounds__(256) void k_scale(float* __restrict__ out,
                                               const float* __restrict__ scale) {
  int n = blockIdx.x;
  float sc = scale[n];
  size_t base = (size_t)n * OUTW;
  int off = (int)((4 - (base & 3)) & 3);
  for (int c = threadIdx.x; c < off; c += 256) out[base + c] *= sc;
  int nv = (VOCAB - off) >> 2;
  f32x4* p = (f32x4*)(out + base + off);
  for (int i = threadIdx.x; i < nv; i += 256) {
    f32x4 v = p[i];
    v *= sc;
    __builtin_nontemporal_store(v, &p[i]);
  }
  for (int c = off + (nv << 2) + threadIdx.x; c < VOCAB; c += 256) out[base + c] *= sc;
}

// ---------------- tier-2: expand shifted bf16 ebuf -> scaled f32 out ---------
__global__ __launch_bounds__(256) void k_scale2(const unsigned short* __restrict__ ebuf,
                                                const float* __restrict__ scale,
                                                float* __restrict__ out) {
  int n = blockIdx.x;
  float sc = scale[n];
  const int shift = n & 3;
  const int off = (4 - shift) & 3;
  const unsigned short* er = ebuf + (size_t)n * VOCABP2 + shift;
  float* orow = out + (size_t)n * OUTW;
  for (int c = threadIdx.x; c < off; c += 256)
    orow[c] = __uint_as_float((unsigned)er[c] << 16) * sc;
  int nv = (VOCAB - off) >> 2;
  for (int i = threadIdx.x; i < nv; i += 256) {
    int c = off + i * 4;
    ushort4 v = *(const ushort4*)(er + c);      // byte offset % 8 == 0
    f32x4 f;
    f.x = __uint_as_float((unsigned)v.x << 16) * sc;
    f.y = __uint_as_float((unsigned)v.y << 16) * sc;
    f.z = __uint_as_float((unsigned)v.z << 16) * sc;
    f.w = __uint_as_float((unsigned)v.w << 16) * sc;
    __builtin_nontemporal_store(f, (f32x4*)(orow + c));
  }
  for (int c = off + (nv << 2) + threadIdx.x; c < VOCAB; c += 256)
    orow[c] = __uint_as_float((unsigned)er[c] << 16) * sc;
}

// ---------------- copy probs: out[:, VOCAB:] = (attn*pc) @ src_map -----------
__global__ __launch_bounds__(64) void k_copy(const float* __restrict__ attn,
                                             const float* __restrict__ src_map,
                                             const float* __restrict__ pc,
                                             float* __restrict__ out) {
  int n = blockIdx.x;
  int c = threadIdx.x;  // 0..63
  int b = n & 31;
  __shared__ float arow[SLEN];
  arow[c] = attn[(size_t)n * SLEN + c];
  arow[c + 64] = attn[(size_t)n * SLEN + 64 + c];
  __syncthreads();
  float s = 0.0f;
  for (int sp = 0; sp < SLEN; sp++)
    s += arow[sp] * src_map[((size_t)sp * 32 + b) * CVOCAB + c];
  out[(size_t)n * OUTW + VOCAB + c] = s * pc[n];
}

extern "C" void kernel_launch(void* const* d_in, const int* in_sizes, int n_in,
                              void* d_out, int out_size, void* d_ws, size_t ws_size,
                              hipStream_t stream) {
  const float* hidden = (const float*)d_in[0];
  const float* attn   = (const float*)d_in[1];
  const float* srcmap = (const float*)d_in[2];
  const float* Wg     = (const float*)d_in[3];
  const float* bg     = (const float*)d_in[4];
  const float* Wc     = (const float*)d_in[5];
  const float* bc     = (const float*)d_in[6];
  float* out = (float*)d_out;

  char* ws = (char*)d_ws;
  float* pc      = (float*)ws;                       // 2048 f32
  float* scale   = (float*)(ws + 8192);              // 2048 f32
  float* partial = (float*)(ws + 16384);             // NVT*2048 f32 (max)
  size_t partEnd = 16384 + (size_t)NVT * NROWS * 4;  // 3,235,840
  unsigned char* A8 = (unsigned char*)(ws + partEnd);            // 2 MB
  size_t aEnd = partEnd + (size_t)NROWS * DDIM;
  unsigned char* W8 = (unsigned char*)(ws + aEnd);               // 51.6 MB
  size_t wEnd = aEnd + (size_t)VOCABP2 * DDIM;
  unsigned short* ebuf = (unsigned short*)(ws + wEnd);           // 206.6 MB
  size_t need1 = wEnd;
  size_t need2 = wEnd + (size_t)NROWS * VOCABP2 * 2;

  k_pcopy<<<NROWS / 4, 256, 0, stream>>>(hidden, Wc, bc, pc);
  if (ws_size >= need1) {
    k_cvtA8<<<(NROWS * DDIM / 4) / 256, 256, 0, stream>>>(hidden, A8);
    k_cvtW8<<<VOCABP2, 256, 0, stream>>>(Wg, W8);
    if (ws_size >= need2) {
      k_gemm8<1><<<8 * NVT2, 512, 0, stream>>>(A8, W8, bg, out, ebuf, partial);
      k_reduce<<<NROWS / 8, 256, 0, stream>>>(partial, pc, scale, NVT2);
      k_scale2<<<NROWS, 256, 0, stream>>>(ebuf, scale, out);
    } else {
      k_gemm8<0><<<8 * NVT2, 512, 0, stream>>>(A8, W8, bg, out, ebuf, partial);
      k_reduce<<<NROWS / 8, 256, 0, stream>>>(partial, pc, scale, NVT2);
      k_scale<<<NROWS, 256, 0, stream>>>(out, scale);
    }
  } else {
    k_gemm<<<dim3(NROWS / 128, NVT), 256, 0, stream>>>(hidden, Wg, bg, out, partial);
    k_reduce<<<NROWS / 8, 256, 0, stream>>>(partial, pc, scale, NVT);
    k_scale<<<NROWS, 256, 0, stream>>>(out, scale);
  }
  k_copy<<<NROWS, 64, 0, stream>>>(attn, srcmap, pc, out);
}